// Round 7
// baseline (853.316 us; speedup 1.0000x reference)
//
#include <hip/hip_runtime.h>
#include <math.h>

#define D_ 256
#define KSLOT 32
#define CAP2 128      // order-2 slots per row (Poisson(30.5), 18 sigma)
#define CAP3C 16      // order-3 c-side slots per row (Poisson(2))
#define CAP3I 32      // order-3 incidence slots per row (Poisson(4))
#define NBP 256       // partition blocks
#define NBUCK 256     // row buckets (128 rows each, N=32768)
typedef unsigned short ushort_t;
typedef __attribute__((ext_vector_type(8))) short bf16x8;
typedef __attribute__((ext_vector_type(4))) float f32x4;
typedef __attribute__((ext_vector_type(2))) float f32x2;

// ---------- helpers ----------
__device__ __forceinline__ float softplus_f(float x){
  return (x > 20.0f) ? x : log1pf(expf(x));
}
__device__ __forceinline__ float bflo(unsigned u){ return __uint_as_float(u << 16); }
__device__ __forceinline__ float bfhi(unsigned u){ return __uint_as_float(u & 0xFFFF0000u); }
__device__ __forceinline__ f32x2 up2(unsigned u){
  f32x2 r; r.x = bflo(u); r.y = bfhi(u); return r;
}
__device__ __forceinline__ ushort_t f2b(float f){
  unsigned u = __float_as_uint(f);
  unsigned r = u + 0x7FFFu + ((u >> 16) & 1u);
  return (ushort_t)(r >> 16);
}
__device__ __forceinline__ unsigned pack2(float a, float b){
  return (unsigned)f2b(a) | ((unsigned)f2b(b) << 16);
}
// uint4 pair -> 8 packed f32x2 (16 bf16 values)
__device__ __forceinline__ void unpack8v(uint4 a, uint4 b, f32x2* v){
  v[0]=up2(a.x); v[1]=up2(a.y); v[2]=up2(a.z); v[3]=up2(a.w);
  v[4]=up2(b.x); v[5]=up2(b.y); v[6]=up2(b.z); v[7]=up2(b.w);
}
__device__ __forceinline__ float block_reduce_sum(float v, float* sbuf){
  #pragma unroll
  for (int o = 32; o > 0; o >>= 1) v += __shfl_xor(v, o);
  int t = threadIdx.x, wid = t >> 6, lane = t & 63;
  if (lane == 0) sbuf[wid] = v;
  __syncthreads();
  if (t == 0) sbuf[0] = sbuf[0] + sbuf[1] + sbuf[2] + sbuf[3];
  __syncthreads();
  float r = sbuf[0];
  __syncthreads();
  return r;
}

// ---------- zero fill ----------
__global__ __launch_bounds__(256) void zerok(float4* __restrict__ p, size_t n4){
  float4 z; z.x = z.y = z.z = z.w = 0.f;
  for (size_t i = (size_t)blockIdx.x * 256 + threadIdx.x; i < n4; i += (size_t)gridDim.x * 256)
    p[i] = z;
}

// ---------- layernorm forward -> bf16 G ----------
__global__ __launch_bounds__(256) void ln_fwd(const float* __restrict__ X, const float* __restrict__ gamma,
    const float* __restrict__ beta, ushort_t* __restrict__ Gb, float* __restrict__ mean, float* __restrict__ rstd)
{
  __shared__ float sbuf[8];
  int n = blockIdx.x, t = threadIdx.x;
  size_t idx = (size_t)n * D_ + t;
  float x = X[idx];
  float mu = block_reduce_sum(x, sbuf) * (1.0f / D_);
  float d = x - mu;
  float var = block_reduce_sum(d * d, sbuf) * (1.0f / D_);
  float rs = rsqrtf(var + 1e-5f);
  Gb[idx] = f2b(d * rs * gamma[t] + beta[t]);
  if (t == 0){ mean[n] = mu; rstd[n] = rs; }
}

// ---------- fused weight prep ----------
__global__ __launch_bounds__(256) void wprep_all(const float* __restrict__ W_Q2, const float* __restrict__ W_K2,
    const float* __restrict__ W_Q3, const float* __restrict__ W_K3, const float* __restrict__ W_Qm,
    ushort_t* __restrict__ WtQm, ushort_t* __restrict__ WtF2, ushort_t* __restrict__ WtF3,
    ushort_t* __restrict__ WbQm, ushort_t* __restrict__ Bt2, ushort_t* __restrict__ Bt3)
{
  int idx = blockIdx.x * 256 + threadIdx.x;
  if (idx < 65536){
    int m = idx >> 8, k = idx & 255;
    WtQm[idx] = f2b(W_Qm[k * 256 + m]);
    return;
  }
  idx -= 65536;
  if (idx < 131072){
    int m = idx >> 8, k = idx & 255;
    WtF2[idx] = f2b(m < 256 ? W_Q2[k * 256 + m] : W_K2[k * 256 + (m - 256)]);
    return;
  }
  idx -= 131072;
  if (idx < 262144){
    int m = idx >> 8, k = idx & 255;
    WtF3[idx] = f2b(m < 512 ? W_Q3[k * 512 + m] : W_K3[k * 512 + (m - 512)]);
    return;
  }
  idx -= 262144;
  if (idx < 65536){ WbQm[idx] = f2b(W_Qm[idx]); return; }
  idx -= 65536;
  if (idx < 131072){
    int d = idx >> 9, k = idx & 511;
    Bt2[idx] = f2b(k < 256 ? W_Q2[d * 256 + k] : W_K2[d * 256 + (k - 256)]);
    return;
  }
  idx -= 131072;
  if (idx < 262144){
    int d = idx >> 10, k = idx & 1023;
    Bt3[idx] = f2b(k < 512 ? W_Q3[d * 512 + k] : W_K3[d * 512 + (k - 512)]);
  }
}

// ---------- MFMA GEMM with async global->LDS staging: C[N,M] op= A[N,K] @ Bt[M,K]^T ----------
template<int OUT_MODE>  // 0 store fp32, 1 accumulate fp32, 2 store bf16
__global__ __launch_bounds__(256) void gemm_bt_mfma(const ushort_t* __restrict__ A,
    const ushort_t* __restrict__ Bt, void* __restrict__ C, int K, int M)
{
  __shared__ __align__(16) ushort_t As[128 * 32];
  __shared__ __align__(16) ushort_t Bs[128 * 32];
  int t = threadIdx.x;
  int wave = t >> 6, lane = t & 63;
  int row0 = blockIdx.y * 128;
  int col0 = blockIdx.x * 128;
  int wrow = (wave & 1) * 64;
  int wcol = (wave >> 1) * 64;
  f32x4 acc[4][4];
  #pragma unroll
  for (int i = 0; i < 4; ++i)
    #pragma unroll
    for (int j = 0; j < 4; ++j)
      acc[i][j] = (f32x4){0.f, 0.f, 0.f, 0.f};
  int srow = wave * 32 + (lane >> 2);
  int skoff = (lane & 3) * 8;
  const ushort_t* Ag0 = A + (size_t)(row0 + srow) * K + skoff;
  const ushort_t* Ag1 = A + (size_t)(row0 + srow + 16) * K + skoff;
  const ushort_t* Bg0 = Bt + (size_t)(col0 + srow) * K + skoff;
  const ushort_t* Bg1 = Bt + (size_t)(col0 + srow + 16) * K + skoff;
  ushort_t* Al0 = As + wave * 1024;
  ushort_t* Al1 = As + wave * 1024 + 512;
  ushort_t* Bl0 = Bs + wave * 1024;
  ushort_t* Bl1 = Bs + wave * 1024 + 512;
  int lrow = lane & 15, lk = (lane >> 4) * 8;
  for (int k0 = 0; k0 < K; k0 += 32){
    __syncthreads();
    __builtin_amdgcn_global_load_lds((const __attribute__((address_space(1))) void*)(Ag0 + k0),
                                     (__attribute__((address_space(3))) void*)Al0, 16, 0, 0);
    __builtin_amdgcn_global_load_lds((const __attribute__((address_space(1))) void*)(Ag1 + k0),
                                     (__attribute__((address_space(3))) void*)Al1, 16, 0, 0);
    __builtin_amdgcn_global_load_lds((const __attribute__((address_space(1))) void*)(Bg0 + k0),
                                     (__attribute__((address_space(3))) void*)Bl0, 16, 0, 0);
    __builtin_amdgcn_global_load_lds((const __attribute__((address_space(1))) void*)(Bg1 + k0),
                                     (__attribute__((address_space(3))) void*)Bl1, 16, 0, 0);
    __syncthreads();
    bf16x8 af[4], bf_[4];
    #pragma unroll
    for (int i = 0; i < 4; ++i)
      af[i] = *(const bf16x8*)(As + (wrow + i * 16 + lrow) * 32 + lk);
    #pragma unroll
    for (int j = 0; j < 4; ++j)
      bf_[j] = *(const bf16x8*)(Bs + (wcol + j * 16 + lrow) * 32 + lk);
    #pragma unroll
    for (int i = 0; i < 4; ++i)
      #pragma unroll
      for (int j = 0; j < 4; ++j)
        acc[i][j] = __builtin_amdgcn_mfma_f32_16x16x32_bf16(af[i], bf_[j], acc[i][j], 0, 0, 0);
  }
  int rbase = row0 + wrow + (lane >> 4) * 4;
  int cbase = col0 + wcol + (lane & 15);
  #pragma unroll
  for (int i = 0; i < 4; ++i){
    #pragma unroll
    for (int r = 0; r < 4; ++r){
      size_t rowoff = (size_t)(rbase + i * 16 + r) * M;
      #pragma unroll
      for (int j = 0; j < 4; ++j){
        int col = cbase + j * 16;
        float v = acc[i][j][r];
        if (OUT_MODE == 0)      ((float*)C)[rowoff + col] = v;
        else if (OUT_MODE == 1) ((float*)C)[rowoff + col] += v;
        else                    ((ushort_t*)C)[rowoff + col] = f2b(v);
      }
    }
  }
}

// ---------- Km = B_mem @ W_Km -> bf16 padded [128,256] ----------
__global__ __launch_bounds__(256) void km_kernel(const float* __restrict__ Bm, const float* __restrict__ W,
    ushort_t* __restrict__ Kmb)
{
  __shared__ float sb[D_];
  int k = blockIdx.x, t = threadIdx.x;
  if (k < KSLOT){
    sb[t] = Bm[(size_t)k * D_ + t];
    __syncthreads();
    float acc = 0.f;
    for (int d = 0; d < D_; ++d) acc += sb[d] * W[(size_t)d * D_ + t];
    Kmb[(size_t)k * D_ + t] = f2b(acc);
  } else {
    Kmb[(size_t)k * D_ + t] = 0;
  }
}

// ---------- mem softmax ----------
__global__ __launch_bounds__(256) void softmax32(const float* __restrict__ Sm, ushort_t* __restrict__ Pb,
    float* __restrict__ lseM, const float* __restrict__ bmp, const float* __restrict__ lmp)
{
  int t = threadIdx.x;
  int r = blockIdx.x * 8 + (t >> 5);
  int lane = t & 31;
  float bs = fminf(softplus_f(*bmp), 5.0f) * 0.0625f;
  float coef = -softplus_f(*lmp) * 0.0625f;
  float s = Sm[(size_t)r * 128 + lane] * bs;
  float m = s;
  #pragma unroll
  for (int o = 16; o > 0; o >>= 1) m = fmaxf(m, __shfl_xor(m, o, 32));
  float e = __expf(s - m);
  float se = e;
  #pragma unroll
  for (int o = 16; o > 0; o >>= 1) se += __shfl_xor(se, o, 32);
  ushort_t* dst = Pb + (size_t)r * 128 + lane;
  dst[0] = f2b(coef * e / se);
  dst[32] = 0; dst[64] = 0; dst[96] = 0;
  if (lane == 0) lseM[r] = m + logf(se);
}

// ================= order-2 CSR build: bucketed, deterministic, coalesced =================
__global__ __launch_bounds__(256) void p2_hist(const unsigned* __restrict__ key, int stride, int NE_, int chunk,
    unsigned* __restrict__ bh)
{
  __shared__ unsigned h[256];
  int t = threadIdx.x, b = blockIdx.x;
  h[t] = 0;
  __syncthreads();
  int s = b * chunk, e = s + chunk; if (e > NE_) e = NE_;
  for (int i = s + t; i < e; i += 256)
    atomicAdd(&h[(key[(size_t)i * stride] >> 7) & 255u], 1u);
  __syncthreads();
  bh[b * 256 + t] = h[t];
}

__global__ __launch_bounds__(256) void p2_scan(unsigned* __restrict__ bh, int nb, unsigned* __restrict__ base)
{
  __shared__ unsigned ss[256];
  int t = threadIdx.x;
  unsigned tot = 0;
  for (int b = 0; b < nb; ++b) tot += bh[b * 256 + t];
  ss[t] = tot;
  __syncthreads();
  #pragma unroll
  for (int o = 1; o < 256; o <<= 1){
    unsigned v = (t >= o) ? ss[t - o] : 0u;
    __syncthreads();
    ss[t] += v;
    __syncthreads();
  }
  unsigned excl = ss[t] - tot;
  base[t] = excl;
  if (t == 255) base[256] = ss[t];
  unsigned run = excl;
  for (int b = 0; b < nb; ++b){
    unsigned v = bh[b * 256 + t];
    bh[b * 256 + t] = run;
    run += v;
  }
}

__global__ __launch_bounds__(256) void p2_place_c(const int* __restrict__ c2, const int* __restrict__ u2,
    int NE_, int chunk, const unsigned* __restrict__ bh, unsigned* __restrict__ part)
{
  __shared__ unsigned cur[256];
  int t = threadIdx.x, b = blockIdx.x;
  cur[t] = bh[b * 256 + t];
  __syncthreads();
  int s = b * chunk, e = s + chunk; if (e > NE_) e = NE_;
  for (int i = s + t; i < e; i += 256){
    unsigned c = (unsigned)c2[i], u = (unsigned)u2[i];
    unsigned dst = atomicAdd(&cur[c >> 7], 1u);
    part[dst] = ((c & 127u) << 15) | u;
  }
}

__global__ __launch_bounds__(256) void p2_fine_c(const unsigned* __restrict__ part, const unsigned* __restrict__ base,
    ushort_t* __restrict__ adjc, int* __restrict__ cntC, uint2* __restrict__ pairsU)
{
  __shared__ unsigned cnt[128];
  __shared__ ushort_t stage[128 * 128];  // 32KB
  int t = threadIdx.x, b = blockIdx.x;
  if (t < 128) cnt[t] = 0;
  __syncthreads();
  int s = (int)base[b], e = (int)base[b + 1];
  for (int i = s + t; i < e; i += 256){
    unsigned w = part[i];
    unsigned r = w >> 15, u = w & 32767u;
    unsigned slot = atomicAdd(&cnt[r], 1u);
    uint2 pr;
    pr.x = u;
    if (slot < 128u){
      stage[r * 128 + slot] = (ushort_t)u;
      pr.y = (((unsigned)b * 128u + r) << 7) | slot;   // gs = (c<<7)|slot
    } else {
      pr.y = 0xFFFFFFFFu;  // dropped (never happens: 18 sigma)
    }
    pairsU[i] = pr;
  }
  __syncthreads();
  if (t < 128) cntC[b * 128 + t] = (int)cnt[t];
  for (int i = t; i < 16384; i += 256)
    adjc[(size_t)b * 16384 + i] = stage[i];
}

__global__ __launch_bounds__(256) void p2_place_u(const uint2* __restrict__ pairs, int NE_, int chunk,
    const unsigned* __restrict__ bh, uint2* __restrict__ part)
{
  __shared__ unsigned cur[256];
  int t = threadIdx.x, b = blockIdx.x;
  cur[t] = bh[b * 256 + t];
  __syncthreads();
  int s = b * chunk, e = s + chunk; if (e > NE_) e = NE_;
  for (int i = s + t; i < e; i += 256){
    uint2 pr = pairs[i];
    unsigned dst = atomicAdd(&cur[pr.x >> 7], 1u);
    part[dst] = pr;
  }
}

__global__ __launch_bounds__(256) void p2_fine_u(const uint2* __restrict__ part, const unsigned* __restrict__ base,
    int* __restrict__ adju, int* __restrict__ cntU)
{
  __shared__ unsigned cnt[128];
  __shared__ unsigned stage[128 * 128];  // 64KB
  int t = threadIdx.x, b = blockIdx.x;
  if (t < 128) cnt[t] = 0;
  __syncthreads();
  int s = (int)base[b], e = (int)base[b + 1];
  for (int i = s + t; i < e; i += 256){
    uint2 pr = part[i];
    if (pr.y == 0xFFFFFFFFu) continue;
    unsigned r = pr.x & 127u;
    unsigned slot = atomicAdd(&cnt[r], 1u);
    if (slot < 128u) stage[r * 128 + slot] = pr.y;
  }
  __syncthreads();
  if (t < 128) cntU[b * 128 + t] = (int)cnt[t];
  for (int i = t; i < 16384; i += 256)
    adju[(size_t)b * 16384 + i] = (int)stage[i];
}

// ---------- order-3: single-pass fixed-cap scatter (small, unchanged) ----------
__global__ __launch_bounds__(256) void scatter3(const int* __restrict__ c3, const int* __restrict__ u3,
    const int* __restrict__ v3, const int* __restrict__ tt, int* __restrict__ cnt3C, int* __restrict__ cnt3I,
    unsigned* __restrict__ adj3c, uint2* __restrict__ adj3i, int NT_)
{
  int e = blockIdx.x * 256 + threadIdx.x;
  if (e >= NT_) return;
  int c = c3[e], u = u3[e], v = v3[e], tau = tt[e];
  int pc = atomicAdd(cnt3C + c, 1);
  if (pc >= CAP3C) return;
  int cslot = (c << 4) + pc;
  adj3c[cslot] = (unsigned)u | ((unsigned)v << 15) | ((unsigned)tau << 30);
  int pu = atomicAdd(cnt3I + u, 1);
  if (pu < CAP3I){
    uint2 eu; eu.x = (unsigned)c | ((unsigned)tau << 15) | ((unsigned)v << 16); eu.y = (unsigned)cslot;
    adj3i[(u << 5) + pu] = eu;
  }
  int pv = atomicAdd(cnt3I + v, 1);
  if (pv < CAP3I){
    uint2 ev; ev.x = (unsigned)c | ((unsigned)tau << 15) | ((unsigned)u << 16); ev.y = (unsigned)cslot;
    adj3i[(v << 5) + pv] = ev;
  }
}

// ---------- order-2 by-c: packed-f32 math, no-max softmax, s2e holds NORMALIZED p ----------
__global__ __launch_bounds__(256) void e2_rowc(const ushort_t* __restrict__ QK2, const int* __restrict__ cntC,
    const ushort_t* __restrict__ adjc, ushort_t* __restrict__ dstage, float* __restrict__ s2e,
    float2* __restrict__ ml2, const float* __restrict__ b2p, const float* __restrict__ l2p)
{
  int wave = threadIdx.x >> 6, lane = threadIdx.x & 63;
  int r = blockIdx.x * 4 + wave;
  int quarter = lane >> 4, sub = lane & 15;
  float b2s = fminf(softplus_f(*b2p), 5.0f) * 0.0625f;
  float lam2 = softplus_f(*l2p);
  int start = r << 7;
  int deg = cntC[r]; if (deg > CAP2) deg = CAP2;
  int end = start + deg;
  const ushort_t* qrow = QK2 + (size_t)r * 512 + sub * 16;
  f32x2 q2[8];
  unpack8v(*(const uint4*)qrow, *(const uint4*)(qrow + 8), q2);
  #pragma unroll
  for (int j = 0; j < 8; ++j) q2[j] *= b2s;   // fold scale: dot yields s directly
  float l = 0.f;
  f32x2 a2[8] = {};
  int p = start + quarter;
  uint4 k0, k1;
  if (p < end){
    const ushort_t* krow = QK2 + (size_t)adjc[p] * 512 + 256 + sub * 16;
    k0 = *(const uint4*)krow; k1 = *(const uint4*)(krow + 8);
  }
  while (p < end){
    int pn = p + 4;
    uint4 n0, n1;
    if (pn < end){
      const ushort_t* krow = QK2 + (size_t)adjc[pn] * 512 + 256 + sub * 16;
      n0 = *(const uint4*)krow; n1 = *(const uint4*)(krow + 8);
    }
    f32x2 k2[8];
    unpack8v(k0, k1, k2);
    f32x2 d2 = {0.f, 0.f};
    #pragma unroll
    for (int j = 0; j < 8; ++j) d2 = __builtin_elementwise_fma(q2[j], k2[j], d2);
    float d = d2.x + d2.y;
    d += __shfl_xor(d, 1); d += __shfl_xor(d, 2); d += __shfl_xor(d, 4); d += __shfl_xor(d, 8);
    float pt = __expf(d);
    if (sub == 0) s2e[p] = pt;
    l += pt;
    f32x2 ptv = {pt, pt};
    #pragma unroll
    for (int j = 0; j < 8; ++j) a2[j] = __builtin_elementwise_fma(ptv, k2[j], a2[j]);
    k0 = n0; k1 = n1; p = pn;
  }
  float L = l;
  L += __shfl_xor(L, 16); L += __shfl_xor(L, 32);
  float av[16];
  #pragma unroll
  for (int j = 0; j < 8; ++j){ av[2 * j] = a2[j].x; av[2 * j + 1] = a2[j].y; }
  #pragma unroll
  for (int j = 0; j < 16; ++j){
    float x = av[j];
    x += __shfl_xor(x, 16); x += __shfl_xor(x, 32);
    av[j] = x;
  }
  float linv = 0.f, coef = 0.f;
  if (deg > 0){ linv = 1.0f / L; coef = -lam2 * 0.0625f * linv; }
  if (lane == 0){
    float2 ml; ml.x = 0.f; ml.y = linv;
    ml2[r] = ml;
  }
  // normalize stored weights in place: rowu reads final pe with one load
  asm volatile("s_waitcnt vmcnt(0)" ::: "memory");
  if (sub == 0){
    for (int pp = start + quarter; pp < end; pp += 4) s2e[pp] *= linv;
  }
  if (quarter == 0){
    ushort_t* dst = dstage + (size_t)r * 512 + sub * 16;
    uint4 p0, p1;
    p0.x = pack2(coef*av[0], coef*av[1]);   p0.y = pack2(coef*av[2], coef*av[3]);
    p0.z = pack2(coef*av[4], coef*av[5]);   p0.w = pack2(coef*av[6], coef*av[7]);
    p1.x = pack2(coef*av[8], coef*av[9]);   p1.y = pack2(coef*av[10], coef*av[11]);
    p1.z = pack2(coef*av[12], coef*av[13]); p1.w = pack2(coef*av[14], coef*av[15]);
    *(uint4*)dst = p0; *(uint4*)(dst + 8) = p1;
  }
}

// ---------- order-2 by-u: pe = s2e[gs] (pre-normalized), packed accum, prefetch ----------
__global__ __launch_bounds__(256) void e2_rowu(const ushort_t* __restrict__ QK2, const int* __restrict__ cntU,
    const int* __restrict__ adju, const float* __restrict__ s2e,
    ushort_t* __restrict__ dstage, const float* __restrict__ l2p)
{
  int wave = threadIdx.x >> 6, lane = threadIdx.x & 63;
  int r = blockIdx.x * 4 + wave;
  int quarter = lane >> 4, sub = lane & 15;
  float lam2 = softplus_f(*l2p);
  int start = r << 7;
  int deg = cntU[r]; if (deg > CAP2) deg = CAP2;
  int end = start + deg;
  f32x2 a2[8] = {};
  int p = start + quarter;
  uint4 q0a, q0b; float pe0 = 0.f;
  if (p < end){
    int gs = adju[p];
    pe0 = s2e[gs];
    const ushort_t* qrow = QK2 + (size_t)(gs >> 7) * 512 + sub * 16;
    q0a = *(const uint4*)qrow; q0b = *(const uint4*)(qrow + 8);
  }
  while (p < end){
    int pn = p + 4;
    uint4 q1a, q1b; float pe1 = 0.f;
    if (pn < end){
      int gs = adju[pn];
      pe1 = s2e[gs];
      const ushort_t* qrow = QK2 + (size_t)(gs >> 7) * 512 + sub * 16;
      q1a = *(const uint4*)qrow; q1b = *(const uint4*)(qrow + 8);
    }
    f32x2 qf2[8];
    unpack8v(q0a, q0b, qf2);
    f32x2 pev = {pe0, pe0};
    #pragma unroll
    for (int j = 0; j < 8; ++j) a2[j] = __builtin_elementwise_fma(pev, qf2[j], a2[j]);
    q0a = q1a; q0b = q1b; pe0 = pe1; p = pn;
  }
  float av[16];
  #pragma unroll
  for (int j = 0; j < 8; ++j){ av[2 * j] = a2[j].x; av[2 * j + 1] = a2[j].y; }
  #pragma unroll
  for (int j = 0; j < 16; ++j){
    float x = av[j];
    x += __shfl_xor(x, 16); x += __shfl_xor(x, 32);
    av[j] = x;
  }
  float coef = -lam2 * 0.0625f;
  if (quarter == 0){
    ushort_t* dst = dstage + (size_t)r * 512 + 256 + sub * 16;
    uint4 p0, p1;
    p0.x = pack2(coef*av[0], coef*av[1]);   p0.y = pack2(coef*av[2], coef*av[3]);
    p0.z = pack2(coef*av[4], coef*av[5]);   p0.w = pack2(coef*av[6], coef*av[7]);
    p1.x = pack2(coef*av[8], coef*av[9]);   p1.y = pack2(coef*av[10], coef*av[11]);
    p1.z = pack2(coef*av[12], coef*av[13]); p1.w = pack2(coef*av[14], coef*av[15]);
    *(uint4*)dst = p0; *(uint4*)(dst + 8) = p1;
  }
}

// ---------- order-3 by-c: packed math, no-max softmax, s3c holds NORMALIZED p ----------
__global__ __launch_bounds__(256) void e3_rowc(const ushort_t* __restrict__ QK3, const float* __restrict__ Tt,
    const int* __restrict__ cnt3C, const unsigned* __restrict__ adj3c, ushort_t* __restrict__ dstage,
    float* __restrict__ s3c, float2* __restrict__ ml3, const float* __restrict__ b3p,
    const float* __restrict__ l3p)
{
  __shared__ float sT[1024];
  int wave = threadIdx.x >> 6, lane = threadIdx.x & 63;
  int r = blockIdx.x * 4 + wave;
  for (int i = threadIdx.x; i < 1024; i += 256) sT[i] = Tt[i];
  __syncthreads();
  float b3s = fminf(softplus_f(*b3p), 5.0f) * 0.0625f;
  float lam3 = softplus_f(*l3p);
  int start = r << 4;
  int deg = cnt3C[r]; if (deg > CAP3C) deg = CAP3C;
  int end = start + deg;
  uint4 qw = *(const uint4*)(QK3 + (size_t)r * 1024 + lane * 8);
  f32x2 q2[4] = {up2(qw.x), up2(qw.y), up2(qw.z), up2(qw.w)};
  #pragma unroll
  for (int j = 0; j < 4; ++j) q2[j] *= b3s;   // fold scale
  f32x2 t0v[4], t1v[4];
  #pragma unroll
  for (int j = 0; j < 4; ++j){
    t0v[j].x = sT[lane * 8 + 2 * j];       t0v[j].y = sT[lane * 8 + 2 * j + 1];
    t1v[j].x = sT[512 + lane * 8 + 2 * j]; t1v[j].y = sT[512 + lane * 8 + 2 * j + 1];
  }
  float l = 0.f;
  f32x2 a2[4] = {};
  int p = start;
  unsigned ent0 = 0; uint4 bw0, cw0;
  if (p < end){
    ent0 = adj3c[p];
    int u = ent0 & 32767, v = (ent0 >> 15) & 32767;
    bw0 = *(const uint4*)(QK3 + (size_t)u * 1024 + 512 + lane * 8);
    cw0 = *(const uint4*)(QK3 + (size_t)v * 1024 + 512 + lane * 8);
  }
  while (p < end){
    int pn = p + 1;
    unsigned ent1 = 0; uint4 bw1, cw1;
    if (pn < end){
      ent1 = adj3c[pn];
      int u = ent1 & 32767, v = (ent1 >> 15) & 32767;
      bw1 = *(const uint4*)(QK3 + (size_t)u * 1024 + 512 + lane * 8);
      cw1 = *(const uint4*)(QK3 + (size_t)v * 1024 + 512 + lane * 8);
    }
    int tau = (ent0 >> 30) & 1;
    f32x2 kb2[4] = {up2(bw0.x), up2(bw0.y), up2(bw0.z), up2(bw0.w)};
    f32x2 kc2[4] = {up2(cw0.x), up2(cw0.y), up2(cw0.z), up2(cw0.w)};
    f32x2 prod2[4];
    f32x2 d2 = {0.f, 0.f};
    #pragma unroll
    for (int j = 0; j < 4; ++j){
      f32x2 tj = tau ? t1v[j] : t0v[j];
      prod2[j] = kb2[j] * kc2[j] * tj;
      d2 = __builtin_elementwise_fma(q2[j], prod2[j], d2);
    }
    float d = d2.x + d2.y;
    #pragma unroll
    for (int o = 32; o > 0; o >>= 1) d += __shfl_xor(d, o);
    float pt = __expf(d);
    if (lane == 0) s3c[p] = pt;
    l += pt;
    f32x2 ptv = {pt, pt};
    #pragma unroll
    for (int j = 0; j < 4; ++j) a2[j] = __builtin_elementwise_fma(ptv, prod2[j], a2[j]);
    ent0 = ent1; bw0 = bw1; cw0 = cw1; p = pn;
  }
  float linv = 0.f, coef = 0.f;
  if (deg > 0){ linv = 1.0f / l; coef = -lam3 * 0.0625f * linv; }
  // normalize stored weights in place (writes were by lane 0; safe after vmcnt drain)
  asm volatile("s_waitcnt vmcnt(0)" ::: "memory");
  if (lane < deg) s3c[start + lane] *= linv;
  uint4 o4;
  o4.x = pack2(coef*a2[0].x, coef*a2[0].y); o4.y = pack2(coef*a2[1].x, coef*a2[1].y);
  o4.z = pack2(coef*a2[2].x, coef*a2[2].y); o4.w = pack2(coef*a2[3].x, coef*a2[3].y);
  *(uint4*)(dstage + (size_t)r * 1024 + lane * 8) = o4;
  if (lane == 0){
    float2 ml; ml.x = 0.f; ml.y = linv;
    ml3[r] = ml;
  }
}

// ---------- order-3 incidence: pe = s3c[y] (pre-normalized), packed, prefetch ----------
__global__ __launch_bounds__(256) void e3_rowi(const ushort_t* __restrict__ QK3, const float* __restrict__ Tt,
    const int* __restrict__ cnt3I, const uint2* __restrict__ adj3i, const float* __restrict__ s3c,
    ushort_t* __restrict__ dstage, const float* __restrict__ l3p)
{
  __shared__ float sT[1024];
  int wave = threadIdx.x >> 6, lane = threadIdx.x & 63;
  int r = blockIdx.x * 4 + wave;
  for (int i = threadIdx.x; i < 1024; i += 256) sT[i] = Tt[i];
  __syncthreads();
  float lam3 = softplus_f(*l3p);
  int start = r << 5;
  int deg = cnt3I[r]; if (deg > CAP3I) deg = CAP3I;
  int end = start + deg;
  f32x2 t0v[4], t1v[4];
  #pragma unroll
  for (int j = 0; j < 4; ++j){
    t0v[j].x = sT[lane * 8 + 2 * j];       t0v[j].y = sT[lane * 8 + 2 * j + 1];
    t1v[j].x = sT[512 + lane * 8 + 2 * j]; t1v[j].y = sT[512 + lane * 8 + 2 * j + 1];
  }
  f32x2 a2[4] = {};
  int p = start;
  uint2 e0; uint4 qw0, ow0; float pe0 = 0.f;
  if (p < end){
    e0 = adj3i[p];
    int c = e0.x & 32767, other = (e0.x >> 16) & 32767;
    pe0 = s3c[e0.y];
    qw0 = *(const uint4*)(QK3 + (size_t)c * 1024 + lane * 8);
    ow0 = *(const uint4*)(QK3 + (size_t)other * 1024 + 512 + lane * 8);
  }
  while (p < end){
    int pn = p + 1;
    uint2 e1; uint4 qw1, ow1; float pe1 = 0.f;
    if (pn < end){
      e1 = adj3i[pn];
      int c = e1.x & 32767, other = (e1.x >> 16) & 32767;
      pe1 = s3c[e1.y];
      qw1 = *(const uint4*)(QK3 + (size_t)c * 1024 + lane * 8);
      ow1 = *(const uint4*)(QK3 + (size_t)other * 1024 + 512 + lane * 8);
    }
    int tau = (e0.x >> 15) & 1;
    f32x2 q2[4]  = {up2(qw0.x), up2(qw0.y), up2(qw0.z), up2(qw0.w)};
    f32x2 ko2[4] = {up2(ow0.x), up2(ow0.y), up2(ow0.z), up2(ow0.w)};
    f32x2 pev = {pe0, pe0};
    #pragma unroll
    for (int j = 0; j < 4; ++j){
      f32x2 tj = tau ? t1v[j] : t0v[j];
      a2[j] = __builtin_elementwise_fma(pev * q2[j], ko2[j] * tj, a2[j]);
    }
    e0 = e1; qw0 = qw1; ow0 = ow1; pe0 = pe1; p = pn;
  }
  float coef = -lam3 * 0.0625f;
  uint4 o4;
  o4.x = pack2(coef*a2[0].x, coef*a2[0].y); o4.y = pack2(coef*a2[1].x, coef*a2[1].y);
  o4.z = pack2(coef*a2[2].x, coef*a2[2].y); o4.w = pack2(coef*a2[3].x, coef*a2[3].y);
  *(uint4*)(dstage + (size_t)r * 1024 + 512 + lane * 8) = o4;
}

// ---------- LN backward + clips + update ----------
__global__ __launch_bounds__(256) void ln_bwd_update(const float* __restrict__ X, const float* __restrict__ dG,
    const float* __restrict__ gamma, const float* __restrict__ mean, const float* __restrict__ rstd,
    const float* __restrict__ step_p, float* __restrict__ out)
{
  __shared__ float sbuf[8];
  int n = blockIdx.x, t = threadIdx.x;
  size_t idx = (size_t)n * D_ + t;
  float x = X[idx];
  float rs = rstd[n];
  float xh = (x - mean[n]) * rs;
  float dxh = dG[idx] * gamma[t];
  float s1 = block_reduce_sum(dxh, sbuf) * (1.0f / D_);
  float s2v = block_reduce_sum(dxh * xh, sbuf) * (1.0f / D_);
  float dx = rs * (dxh - s1 - xh * s2v);
  float gn2 = block_reduce_sum(dx * dx, sbuf);
  float gn = fmaxf(sqrtf(gn2), 1e-6f);
  float gsc = fminf(1.0f / gn, 1.0f);
  float stp = step_p[0] * 0.9999f;
  float xn = x - stp * gsc * dx;
  float sn2 = block_reduce_sum(xn * xn, sbuf);
  float sn = fmaxf(sqrtf(sn2), 1e-6f);
  float ssc = fminf(10.0f / sn, 1.0f);
  out[idx] = xn * ssc;
}

// ---------- parallel energy partial reduction: atomicAdd into eacc[0..2] ----------
__global__ __launch_bounds__(256) void energy_partial(const float2* __restrict__ ml2, const float2* __restrict__ ml3,
    const float* __restrict__ lseM, int n, float* __restrict__ eacc)
{
  __shared__ float sbuf[8];
  int t = threadIdx.x;
  float a2 = 0.f, a3 = 0.f, am = 0.f;
  for (int i = blockIdx.x * 256 + t; i < n; i += gridDim.x * 256){
    float2 v2 = ml2[i];
    if (v2.y > 0.f) a2 += v2.x - logf(v2.y);
    float2 v3 = ml3[i];
    if (v3.y > 0.f) a3 += v3.x - logf(v3.y);
    am += lseM[i];
  }
  float s2 = block_reduce_sum(a2, sbuf);
  float s3 = block_reduce_sum(a3, sbuf);
  float sm = block_reduce_sum(am, sbuf);
  if (t == 0){
    atomicAdd(eacc + 0, s2);
    atomicAdd(eacc + 1, s3);
    atomicAdd(eacc + 2, sm);
  }
}

// ---------- final combine ----------
__global__ __launch_bounds__(64) void energy_combine(const float* __restrict__ eacc,
    const float* l2p, const float* l3p, const float* lmp,
    const float* b2p, const float* b3p, const float* bmp, float* __restrict__ outE)
{
  if (threadIdx.x == 0){
    float l2 = softplus_f(*l2p), l3 = softplus_f(*l3p), lm = softplus_f(*lmp);
    float b2 = fminf(softplus_f(*b2p), 5.0f);
    float b3 = fminf(softplus_f(*b3p), 5.0f);
    float bm = fminf(softplus_f(*bmp), 5.0f);
    *outE = -(l2 / b2) * eacc[0] - (l3 / b3) * eacc[1] - (lm / bm) * eacc[2];
  }
}

static inline void zfill(void* p, size_t nElems, hipStream_t stream){
  size_t n4 = nElems / 4;
  int blocks = (int)(((n4 + 255) / 256) < 16384 ? ((n4 + 255) / 256) : 16384);
  if (blocks < 1) blocks = 1;
  zerok<<<blocks, 256, 0, stream>>>((float4*)p, n4);
}

extern "C" void kernel_launch(void* const* d_in, const int* in_sizes, int n_in,
                              void* d_out, int out_size, void* d_ws, size_t ws_size,
                              hipStream_t stream)
{
  const float* X     = (const float*)d_in[0];
  const int*   c2    = (const int*)d_in[1];
  const int*   u2    = (const int*)d_in[2];
  const int*   c3    = (const int*)d_in[3];
  const int*   u3    = (const int*)d_in[4];
  const int*   v3    = (const int*)d_in[5];
  const int*   tt    = (const int*)d_in[6];
  const float* stepp = (const float*)d_in[7];
  const float* gamma = (const float*)d_in[8];
  const float* beta  = (const float*)d_in[9];
  const float* W_Q2  = (const float*)d_in[10];
  const float* W_K2  = (const float*)d_in[11];
  const float* W_Q3  = (const float*)d_in[12];
  const float* W_K3  = (const float*)d_in[13];
  const float* T_tau = (const float*)d_in[14];
  const float* W_Qm  = (const float*)d_in[15];
  const float* W_Km  = (const float*)d_in[16];
  const float* B_mem = (const float*)d_in[17];
  const float* l2p   = (const float*)d_in[18];
  const float* l3p   = (const float*)d_in[19];
  const float* lmp   = (const float*)d_in[20];
  const float* b2p   = (const float*)d_in[21];
  const float* b3p   = (const float*)d_in[22];
  const float* bmp   = (const float*)d_in[23];

  const int N  = in_sizes[0] / D_;
  const int NE = in_sizes[1];
  const int NT = in_sizes[3];
  const size_t ND = (size_t)N * D_;

  // ---- byte arena ----
  char* base = (char*)d_ws;
  size_t off = 0;
  auto alloc = [&](size_t bytes) -> void* {
    void* p = base + off;
    off += (bytes + 255) & ~(size_t)255;
    return p;
  };
  ushort_t* Gb    = (ushort_t*)alloc(ND * 2);                    // 16 MB
  ushort_t* bufA  = (ushort_t*)alloc(ND * 4 * 2);                // 64 MB
  ushort_t* bufB  = (ushort_t*)alloc(ND * 4 * 2);                // 64 MB (o2: dstage 32MB | s2e 16MB)
  int*      zreg  = (int*)     alloc(((size_t)4 * N + 16) * 4);  // cntC|cntU|cnt3C|cnt3I|eacc
  ushort_t* adjc  = (ushort_t*)alloc((size_t)N * CAP2 * 2);      // 8 MB (ushort entries)
  int*      adju  = (int*)     alloc((size_t)N * CAP2 * 4);      // 16 MB
  unsigned* adj3c = (unsigned*)alloc((size_t)N * CAP3C * 4);     // 2 MB
  uint2*    adj3i = (uint2*)   alloc((size_t)N * CAP3I * 8);     // 8 MB
  float*    s3c   = (float*)   alloc((size_t)N * CAP3C * 4);     // 2 MB
  float2*   ml2   = (float2*)  alloc((size_t)N * 8);
  float2*   ml3   = (float2*)  alloc((size_t)N * 8);
  ushort_t* Kmb   = (ushort_t*)alloc((size_t)128 * 256 * 2);
  ushort_t* KWb   = (ushort_t*)alloc((size_t)256 * 128 * 2);
  float*    meanb = (float*)   alloc((size_t)N * 4);
  float*    rstdb = (float*)   alloc((size_t)N * 4);
  float*    lseM  = (float*)   alloc((size_t)N * 4);
  ushort_t* WtQm  = (ushort_t*)alloc(65536 * 2);
  ushort_t* WtF2  = (ushort_t*)alloc(131072 * 2);
  ushort_t* WtF3  = (ushort_t*)alloc(262144 * 2);
  ushort_t* WbQm  = (ushort_t*)alloc(65536 * 2);
  ushort_t* Bt2   = (ushort_t*)alloc(131072 * 2);
  ushort_t* Bt3   = (ushort_t*)alloc(262144 * 2);

  int* cntC  = zreg;
  int* cntU  = zreg + N;
  int* cnt3C = zreg + 2 * N;
  int* cnt3I = zreg + 3 * N;
  float* eacc = (float*)(zreg + 4 * N);
  float* out = (float*)d_out;
  float*    Sm  = (float*)bufB;                          // mem phase
  ushort_t* Pb  = (ushort_t*)(Sm + (size_t)N * 128);
  float*    s2e = (float*)(bufB + ND * 2);               // o2 phase: upper 32MB of bufB

  // order-2 build scratch aliased into bufA (dead before the first GEMM writes bufA)
  unsigned* partA  = (unsigned*)bufA;                                 // 8MB: part_c then part_u (uint2)
  uint2*    pairsU = (uint2*)((char*)bufA + ((size_t)8 << 20));       // 8MB
  unsigned* bhC    = (unsigned*)((char*)bufA + ((size_t)16 << 20));   // 256KB
  unsigned* bhU    = bhC + NBP * 256;                                 // 256KB
  unsigned* baseC  = bhU + NBP * 256;                                 // 257 words
  unsigned* baseU  = baseC + 512;

  zfill(zreg, (size_t)4 * N + 16, stream);

  // 1. LN forward + weight prep
  ln_fwd<<<N, 256, 0, stream>>>(X, gamma, beta, Gb, meanb, rstdb);
  wprep_all<<<(917504 + 255) / 256, 256, 0, stream>>>(W_Q2, W_K2, W_Q3, W_K3, W_Qm,
      WtQm, WtF2, WtF3, WbQm, Bt2, Bt3);

  // CSR build order-2: deterministic bucketed build, coalesced writes, zero global atomics
  {
    int chunk = (NE + NBP - 1) / NBP;
    p2_hist<<<NBP, 256, 0, stream>>>((const unsigned*)c2, 1, NE, chunk, bhC);
    p2_scan<<<1, 256, 0, stream>>>(bhC, NBP, baseC);
    p2_place_c<<<NBP, 256, 0, stream>>>(c2, u2, NE, chunk, bhC, partA);
    p2_fine_c<<<NBUCK, 256, 0, stream>>>(partA, baseC, adjc, cntC, pairsU);
    p2_hist<<<NBP, 256, 0, stream>>>((const unsigned*)pairsU, 2, NE, chunk, bhU);
    p2_scan<<<1, 256, 0, stream>>>(bhU, NBP, baseU);
    p2_place_u<<<NBP, 256, 0, stream>>>(pairsU, NE, chunk, bhU, (uint2*)partA);
    p2_fine_u<<<NBUCK, 256, 0, stream>>>((const uint2*)partA, baseU, adju, cntU);
  }
  // order-3 build (small)
  scatter3<<<(NT + 255) / 256, 256, 0, stream>>>(c3, u3, v3, tt, cnt3C, cnt3I, adj3c, adj3i, NT);

  dim3 g256(2, N / 128), g512(4, N / 128), g1024(8, N / 128);

  // 2. memory phase (GEMM-shaped)
  km_kernel<<<128, 256, 0, stream>>>(B_mem, W_Km, Kmb);
  gemm_bt_mfma<2><<<dim3(1, 2), 256, 0, stream>>>(WbQm, Kmb, KWb, 256, 128);
  gemm_bt_mfma<2><<<g256, 256, 0, stream>>>(Gb, WtQm, bufA, D_, D_);
  gemm_bt_mfma<0><<<dim3(1, N / 128), 256, 0, stream>>>(bufA, Kmb, Sm, 256, 128);
  softmax32<<<N / 8, 256, 0, stream>>>(Sm, Pb, lseM, bmp, lmp);
  gemm_bt_mfma<0><<<g256, 256, 0, stream>>>(Pb, KWb, out, 128, D_);

  // 3. order-2 phase
  gemm_bt_mfma<2><<<g512, 256, 0, stream>>>(Gb, WtF2, bufA, D_, 512);
  e2_rowc<<<N / 4, 256, 0, stream>>>(bufA, cntC, adjc, bufB, s2e, ml2, b2p, l2p);
  e2_rowu<<<N / 4, 256, 0, stream>>>(bufA, cntU, adju, s2e, bufB, l2p);
  gemm_bt_mfma<1><<<g256, 256, 0, stream>>>(bufB, Bt2, out, 512, D_);

  // 4. order-3 phase
  gemm_bt_mfma<2><<<g1024, 256, 0, stream>>>(Gb, WtF3, bufA, D_, 1024);
  e3_rowc<<<N / 4, 256, 0, stream>>>(bufA, T_tau, cnt3C, adj3c, bufB, s3c, ml3, b3p, l3p);
  e3_rowi<<<N / 4, 256, 0, stream>>>(bufA, T_tau, cnt3I, adj3i, s3c, bufB, l3p);
  gemm_bt_mfma<1><<<g256, 256, 0, stream>>>(bufB, Bt3, out, 1024, D_);

  // 5. LN backward + clips + update
  ln_bwd_update<<<N, 256, 0, stream>>>(X, out, gamma, meanb, rstdb, stepp, out);

  // 6. energy: parallel partial + tiny combine
  energy_partial<<<128, 256, 0, stream>>>(ml2, ml3, lseM, N, eacc);
  energy_combine<<<1, 64, 0, stream>>>(eacc, l2p, l3p, lmp, b2p, b3p, bmp, out + ND);
}

// Round 8
// 827.534 us; speedup vs baseline: 1.0312x; 1.0312x over previous
//
#include <hip/hip_runtime.h>
#include <math.h>

#define D_ 256
#define KSLOT 32
#define CAP2 128      // order-2 slots per row (Poisson(30.5), 18 sigma)
#define CAP3C 16      // order-3 c-side slots per row (Poisson(2))
#define CAP3I 32      // order-3 incidence slots per row (Poisson(4))
#define NBP 256       // partition blocks
#define NBUCK 256     // row buckets (128 rows each, N=32768)
typedef unsigned short ushort_t;
typedef __attribute__((ext_vector_type(8))) short bf16x8;
typedef __attribute__((ext_vector_type(4))) float f32x4;

// ---------- helpers ----------
__device__ __forceinline__ float softplus_f(float x){
  return (x > 20.0f) ? x : log1pf(expf(x));
}
__device__ __forceinline__ float bflo(unsigned u){ return __uint_as_float(u << 16); }
__device__ __forceinline__ float bfhi(unsigned u){ return __uint_as_float(u & 0xFFFF0000u); }
__device__ __forceinline__ ushort_t f2b(float f){
  unsigned u = __float_as_uint(f);
  unsigned r = u + 0x7FFFu + ((u >> 16) & 1u);
  return (ushort_t)(r >> 16);
}
__device__ __forceinline__ unsigned pack2(float a, float b){
  return (unsigned)f2b(a) | ((unsigned)f2b(b) << 16);
}
__device__ __forceinline__ void unpack16(uint4 a, uint4 b, float* f){
  f[0]=bflo(a.x); f[1]=bfhi(a.x); f[2]=bflo(a.y); f[3]=bfhi(a.y);
  f[4]=bflo(a.z); f[5]=bfhi(a.z); f[6]=bflo(a.w); f[7]=bfhi(a.w);
  f[8]=bflo(b.x); f[9]=bfhi(b.x); f[10]=bflo(b.y); f[11]=bfhi(b.y);
  f[12]=bflo(b.z); f[13]=bfhi(b.z); f[14]=bflo(b.w); f[15]=bfhi(b.w);
}
__device__ __forceinline__ float block_reduce_sum(float v, float* sbuf){
  #pragma unroll
  for (int o = 32; o > 0; o >>= 1) v += __shfl_xor(v, o);
  int t = threadIdx.x, wid = t >> 6, lane = t & 63;
  if (lane == 0) sbuf[wid] = v;
  __syncthreads();
  if (t == 0) sbuf[0] = sbuf[0] + sbuf[1] + sbuf[2] + sbuf[3];
  __syncthreads();
  float r = sbuf[0];
  __syncthreads();
  return r;
}

// ---------- zero fill ----------
__global__ __launch_bounds__(256) void zerok(float4* __restrict__ p, size_t n4){
  float4 z; z.x = z.y = z.z = z.w = 0.f;
  for (size_t i = (size_t)blockIdx.x * 256 + threadIdx.x; i < n4; i += (size_t)gridDim.x * 256)
    p[i] = z;
}

// ---------- layernorm forward -> bf16 G ----------
__global__ __launch_bounds__(256) void ln_fwd(const float* __restrict__ X, const float* __restrict__ gamma,
    const float* __restrict__ beta, ushort_t* __restrict__ Gb, float* __restrict__ mean, float* __restrict__ rstd)
{
  __shared__ float sbuf[8];
  int n = blockIdx.x, t = threadIdx.x;
  size_t idx = (size_t)n * D_ + t;
  float x = X[idx];
  float mu = block_reduce_sum(x, sbuf) * (1.0f / D_);
  float d = x - mu;
  float var = block_reduce_sum(d * d, sbuf) * (1.0f / D_);
  float rs = rsqrtf(var + 1e-5f);
  Gb[idx] = f2b(d * rs * gamma[t] + beta[t]);
  if (t == 0){ mean[n] = mu; rstd[n] = rs; }
}

// ---------- fused weight prep ----------
__global__ __launch_bounds__(256) void wprep_all(const float* __restrict__ W_Q2, const float* __restrict__ W_K2,
    const float* __restrict__ W_Q3, const float* __restrict__ W_K3, const float* __restrict__ W_Qm,
    ushort_t* __restrict__ WtQm, ushort_t* __restrict__ WtF2, ushort_t* __restrict__ WtF3,
    ushort_t* __restrict__ WbQm, ushort_t* __restrict__ Bt2, ushort_t* __restrict__ Bt3)
{
  int idx = blockIdx.x * 256 + threadIdx.x;
  if (idx < 65536){
    int m = idx >> 8, k = idx & 255;
    WtQm[idx] = f2b(W_Qm[k * 256 + m]);
    return;
  }
  idx -= 65536;
  if (idx < 131072){
    int m = idx >> 8, k = idx & 255;
    WtF2[idx] = f2b(m < 256 ? W_Q2[k * 256 + m] : W_K2[k * 256 + (m - 256)]);
    return;
  }
  idx -= 131072;
  if (idx < 262144){
    int m = idx >> 8, k = idx & 255;
    WtF3[idx] = f2b(m < 512 ? W_Q3[k * 512 + m] : W_K3[k * 512 + (m - 512)]);
    return;
  }
  idx -= 262144;
  if (idx < 65536){ WbQm[idx] = f2b(W_Qm[idx]); return; }
  idx -= 65536;
  if (idx < 131072){
    int d = idx >> 9, k = idx & 511;
    Bt2[idx] = f2b(k < 256 ? W_Q2[d * 256 + k] : W_K2[d * 256 + (k - 256)]);
    return;
  }
  idx -= 131072;
  if (idx < 262144){
    int d = idx >> 10, k = idx & 1023;
    Bt3[idx] = f2b(k < 512 ? W_Q3[d * 512 + k] : W_K3[d * 512 + (k - 512)]);
  }
}

// ---------- MFMA GEMM with async global->LDS staging: C[N,M] op= A[N,K] @ Bt[M,K]^T ----------
template<int OUT_MODE>  // 0 store fp32, 1 accumulate fp32, 2 store bf16
__global__ __launch_bounds__(256) void gemm_bt_mfma(const ushort_t* __restrict__ A,
    const ushort_t* __restrict__ Bt, void* __restrict__ C, int K, int M)
{
  __shared__ __align__(16) ushort_t As[128 * 32];
  __shared__ __align__(16) ushort_t Bs[128 * 32];
  int t = threadIdx.x;
  int wave = t >> 6, lane = t & 63;
  int row0 = blockIdx.y * 128;
  int col0 = blockIdx.x * 128;
  int wrow = (wave & 1) * 64;
  int wcol = (wave >> 1) * 64;
  f32x4 acc[4][4];
  #pragma unroll
  for (int i = 0; i < 4; ++i)
    #pragma unroll
    for (int j = 0; j < 4; ++j)
      acc[i][j] = (f32x4){0.f, 0.f, 0.f, 0.f};
  int srow = wave * 32 + (lane >> 2);
  int skoff = (lane & 3) * 8;
  const ushort_t* Ag0 = A + (size_t)(row0 + srow) * K + skoff;
  const ushort_t* Ag1 = A + (size_t)(row0 + srow + 16) * K + skoff;
  const ushort_t* Bg0 = Bt + (size_t)(col0 + srow) * K + skoff;
  const ushort_t* Bg1 = Bt + (size_t)(col0 + srow + 16) * K + skoff;
  ushort_t* Al0 = As + wave * 1024;
  ushort_t* Al1 = As + wave * 1024 + 512;
  ushort_t* Bl0 = Bs + wave * 1024;
  ushort_t* Bl1 = Bs + wave * 1024 + 512;
  int lrow = lane & 15, lk = (lane >> 4) * 8;
  for (int k0 = 0; k0 < K; k0 += 32){
    __syncthreads();
    __builtin_amdgcn_global_load_lds((const __attribute__((address_space(1))) void*)(Ag0 + k0),
                                     (__attribute__((address_space(3))) void*)Al0, 16, 0, 0);
    __builtin_amdgcn_global_load_lds((const __attribute__((address_space(1))) void*)(Ag1 + k0),
                                     (__attribute__((address_space(3))) void*)Al1, 16, 0, 0);
    __builtin_amdgcn_global_load_lds((const __attribute__((address_space(1))) void*)(Bg0 + k0),
                                     (__attribute__((address_space(3))) void*)Bl0, 16, 0, 0);
    __builtin_amdgcn_global_load_lds((const __attribute__((address_space(1))) void*)(Bg1 + k0),
                                     (__attribute__((address_space(3))) void*)Bl1, 16, 0, 0);
    __syncthreads();
    bf16x8 af[4], bf_[4];
    #pragma unroll
    for (int i = 0; i < 4; ++i)
      af[i] = *(const bf16x8*)(As + (wrow + i * 16 + lrow) * 32 + lk);
    #pragma unroll
    for (int j = 0; j < 4; ++j)
      bf_[j] = *(const bf16x8*)(Bs + (wcol + j * 16 + lrow) * 32 + lk);
    #pragma unroll
    for (int i = 0; i < 4; ++i)
      #pragma unroll
      for (int j = 0; j < 4; ++j)
        acc[i][j] = __builtin_amdgcn_mfma_f32_16x16x32_bf16(af[i], bf_[j], acc[i][j], 0, 0, 0);
  }
  int rbase = row0 + wrow + (lane >> 4) * 4;
  int cbase = col0 + wcol + (lane & 15);
  #pragma unroll
  for (int i = 0; i < 4; ++i){
    #pragma unroll
    for (int r = 0; r < 4; ++r){
      size_t rowoff = (size_t)(rbase + i * 16 + r) * M;
      #pragma unroll
      for (int j = 0; j < 4; ++j){
        int col = cbase + j * 16;
        float v = acc[i][j][r];
        if (OUT_MODE == 0)      ((float*)C)[rowoff + col] = v;
        else if (OUT_MODE == 1) ((float*)C)[rowoff + col] += v;
        else                    ((ushort_t*)C)[rowoff + col] = f2b(v);
      }
    }
  }
}

// ---------- Km = B_mem @ W_Km -> bf16 padded [128,256] ----------
__global__ __launch_bounds__(256) void km_kernel(const float* __restrict__ Bm, const float* __restrict__ W,
    ushort_t* __restrict__ Kmb)
{
  __shared__ float sb[D_];
  int k = blockIdx.x, t = threadIdx.x;
  if (k < KSLOT){
    sb[t] = Bm[(size_t)k * D_ + t];
    __syncthreads();
    float acc = 0.f;
    for (int d = 0; d < D_; ++d) acc += sb[d] * W[(size_t)d * D_ + t];
    Kmb[(size_t)k * D_ + t] = f2b(acc);
  } else {
    Kmb[(size_t)k * D_ + t] = 0;
  }
}

// ---------- mem softmax ----------
__global__ __launch_bounds__(256) void softmax32(const float* __restrict__ Sm, ushort_t* __restrict__ Pb,
    float* __restrict__ lseM, const float* __restrict__ bmp, const float* __restrict__ lmp)
{
  int t = threadIdx.x;
  int r = blockIdx.x * 8 + (t >> 5);
  int lane = t & 31;
  float bs = fminf(softplus_f(*bmp), 5.0f) * 0.0625f;
  float coef = -softplus_f(*lmp) * 0.0625f;
  float s = Sm[(size_t)r * 128 + lane] * bs;
  float m = s;
  #pragma unroll
  for (int o = 16; o > 0; o >>= 1) m = fmaxf(m, __shfl_xor(m, o, 32));
  float e = __expf(s - m);
  float se = e;
  #pragma unroll
  for (int o = 16; o > 0; o >>= 1) se += __shfl_xor(se, o, 32);
  ushort_t* dst = Pb + (size_t)r * 128 + lane;
  dst[0] = f2b(coef * e / se);
  dst[32] = 0; dst[64] = 0; dst[96] = 0;
  if (lane == 0) lseM[r] = m + logf(se);
}

// ================= order-2 CSR build: bucketed, deterministic, coalesced =================
__global__ __launch_bounds__(256) void p2_hist(const unsigned* __restrict__ key, int stride, int NE_, int chunk,
    unsigned* __restrict__ bh)
{
  __shared__ unsigned h[256];
  int t = threadIdx.x, b = blockIdx.x;
  h[t] = 0;
  __syncthreads();
  int s = b * chunk, e = s + chunk; if (e > NE_) e = NE_;
  for (int i = s + t; i < e; i += 256)
    atomicAdd(&h[(key[(size_t)i * stride] >> 7) & 255u], 1u);
  __syncthreads();
  bh[b * 256 + t] = h[t];
}

__global__ __launch_bounds__(256) void p2_scan(unsigned* __restrict__ bh, int nb, unsigned* __restrict__ base)
{
  __shared__ unsigned ss[256];
  int t = threadIdx.x;
  unsigned tot = 0;
  for (int b = 0; b < nb; ++b) tot += bh[b * 256 + t];
  ss[t] = tot;
  __syncthreads();
  #pragma unroll
  for (int o = 1; o < 256; o <<= 1){
    unsigned v = (t >= o) ? ss[t - o] : 0u;
    __syncthreads();
    ss[t] += v;
    __syncthreads();
  }
  unsigned excl = ss[t] - tot;
  base[t] = excl;
  if (t == 255) base[256] = ss[t];
  unsigned run = excl;
  for (int b = 0; b < nb; ++b){
    unsigned v = bh[b * 256 + t];
    bh[b * 256 + t] = run;
    run += v;
  }
}

__global__ __launch_bounds__(256) void p2_place_c(const int* __restrict__ c2, const int* __restrict__ u2,
    int NE_, int chunk, const unsigned* __restrict__ bh, unsigned* __restrict__ part)
{
  __shared__ unsigned cur[256];
  int t = threadIdx.x, b = blockIdx.x;
  cur[t] = bh[b * 256 + t];
  __syncthreads();
  int s = b * chunk, e = s + chunk; if (e > NE_) e = NE_;
  for (int i = s + t; i < e; i += 256){
    unsigned c = (unsigned)c2[i], u = (unsigned)u2[i];
    unsigned dst = atomicAdd(&cur[c >> 7], 1u);
    part[dst] = ((c & 127u) << 15) | u;
  }
}

__global__ __launch_bounds__(256) void p2_fine_c(const unsigned* __restrict__ part, const unsigned* __restrict__ base,
    ushort_t* __restrict__ adjc, int* __restrict__ cntC, uint2* __restrict__ pairsU)
{
  __shared__ unsigned cnt[128];
  __shared__ ushort_t stage[128 * 128];  // 32KB
  int t = threadIdx.x, b = blockIdx.x;
  if (t < 128) cnt[t] = 0;
  __syncthreads();
  int s = (int)base[b], e = (int)base[b + 1];
  for (int i = s + t; i < e; i += 256){
    unsigned w = part[i];
    unsigned r = w >> 15, u = w & 32767u;
    unsigned slot = atomicAdd(&cnt[r], 1u);
    uint2 pr;
    pr.x = u;
    if (slot < 128u){
      stage[r * 128 + slot] = (ushort_t)u;
      pr.y = (((unsigned)b * 128u + r) << 7) | slot;   // gs = (c<<7)|slot
    } else {
      pr.y = 0xFFFFFFFFu;  // dropped (never happens: 18 sigma)
    }
    pairsU[i] = pr;
  }
  __syncthreads();
  if (t < 128) cntC[b * 128 + t] = (int)cnt[t];
  for (int i = t; i < 16384; i += 256)
    adjc[(size_t)b * 16384 + i] = stage[i];
}

__global__ __launch_bounds__(256) void p2_place_u(const uint2* __restrict__ pairs, int NE_, int chunk,
    const unsigned* __restrict__ bh, uint2* __restrict__ part)
{
  __shared__ unsigned cur[256];
  int t = threadIdx.x, b = blockIdx.x;
  cur[t] = bh[b * 256 + t];
  __syncthreads();
  int s = b * chunk, e = s + chunk; if (e > NE_) e = NE_;
  for (int i = s + t; i < e; i += 256){
    uint2 pr = pairs[i];
    unsigned dst = atomicAdd(&cur[pr.x >> 7], 1u);
    part[dst] = pr;
  }
}

__global__ __launch_bounds__(256) void p2_fine_u(const uint2* __restrict__ part, const unsigned* __restrict__ base,
    int* __restrict__ adju, int* __restrict__ cntU)
{
  __shared__ unsigned cnt[128];
  __shared__ unsigned stage[128 * 128];  // 64KB
  int t = threadIdx.x, b = blockIdx.x;
  if (t < 128) cnt[t] = 0;
  __syncthreads();
  int s = (int)base[b], e = (int)base[b + 1];
  for (int i = s + t; i < e; i += 256){
    uint2 pr = part[i];
    if (pr.y == 0xFFFFFFFFu) continue;
    unsigned r = pr.x & 127u;
    unsigned slot = atomicAdd(&cnt[r], 1u);
    if (slot < 128u) stage[r * 128 + slot] = pr.y;
  }
  __syncthreads();
  if (t < 128) cntU[b * 128 + t] = (int)cnt[t];
  for (int i = t; i < 16384; i += 256)
    adju[(size_t)b * 16384 + i] = (int)stage[i];
}

// ---------- order-3: single-pass fixed-cap scatter (small, unchanged) ----------
__global__ __launch_bounds__(256) void scatter3(const int* __restrict__ c3, const int* __restrict__ u3,
    const int* __restrict__ v3, const int* __restrict__ tt, int* __restrict__ cnt3C, int* __restrict__ cnt3I,
    unsigned* __restrict__ adj3c, uint2* __restrict__ adj3i, int NT_)
{
  int e = blockIdx.x * 256 + threadIdx.x;
  if (e >= NT_) return;
  int c = c3[e], u = u3[e], v = v3[e], tau = tt[e];
  int pc = atomicAdd(cnt3C + c, 1);
  if (pc >= CAP3C) return;
  int cslot = (c << 4) + pc;
  adj3c[cslot] = (unsigned)u | ((unsigned)v << 15) | ((unsigned)tau << 30);
  int pu = atomicAdd(cnt3I + u, 1);
  if (pu < CAP3I){
    uint2 eu; eu.x = (unsigned)c | ((unsigned)tau << 15) | ((unsigned)v << 16); eu.y = (unsigned)cslot;
    adj3i[(u << 5) + pu] = eu;
  }
  int pv = atomicAdd(cnt3I + v, 1);
  if (pv < CAP3I){
    uint2 ev; ev.x = (unsigned)c | ((unsigned)tau << 15) | ((unsigned)u << 16); ev.y = (unsigned)cslot;
    adj3i[(v << 5) + pv] = ev;
  }
}

// ---------- order-2 by-c: 16 lanes/edge, no-max softmax, 32-bit gather offsets, prefetch ----------
// s2e stores exp(s) directly; ml2 = {0, 1/L}.
__global__ __launch_bounds__(256) void e2_rowc(const ushort_t* __restrict__ QK2, const int* __restrict__ cntC,
    const ushort_t* __restrict__ adjc, ushort_t* __restrict__ dstage, float* __restrict__ s2e,
    float2* __restrict__ ml2, const float* __restrict__ b2p, const float* __restrict__ l2p)
{
  int wave = threadIdx.x >> 6, lane = threadIdx.x & 63;
  int r = blockIdx.x * 4 + wave;
  int quarter = lane >> 4, sub = lane & 15;
  float b2s = fminf(softplus_f(*b2p), 5.0f) * 0.0625f;
  float lam2 = softplus_f(*l2p);
  int start = r << 7;
  int deg = cntC[r]; if (deg > CAP2) deg = CAP2;
  int end = start + deg;
  unsigned subo = (unsigned)sub * 16u;
  const ushort_t* qrow = QK2 + ((unsigned)r << 9) + subo;
  float qf[16];
  unpack16(*(const uint4*)qrow, *(const uint4*)(qrow + 8), qf);
  #pragma unroll
  for (int j = 0; j < 16; ++j) qf[j] *= b2s;   // fold scale: dot yields s directly
  float l = 0.f;
  float a[16] = {};
  int p = start + quarter;
  uint4 k0, k1;
  if (p < end){
    unsigned off = ((unsigned)adjc[p] << 9) + 256u + subo;   // 32-bit element offset
    k0 = *(const uint4*)(QK2 + off); k1 = *(const uint4*)(QK2 + off + 8);
  }
  while (p < end){
    int pn = p + 4;
    uint4 n0, n1;
    if (pn < end){
      unsigned off = ((unsigned)adjc[pn] << 9) + 256u + subo;
      n0 = *(const uint4*)(QK2 + off); n1 = *(const uint4*)(QK2 + off + 8);
    }
    float kf[16];
    unpack16(k0, k1, kf);
    float d = 0.f;
    #pragma unroll
    for (int j = 0; j < 16; ++j) d += qf[j] * kf[j];
    d += __shfl_xor(d, 1); d += __shfl_xor(d, 2); d += __shfl_xor(d, 4); d += __shfl_xor(d, 8);
    float pt = __expf(d);
    if (sub == 0) s2e[p] = pt;
    l += pt;
    #pragma unroll
    for (int j = 0; j < 16; ++j) a[j] += pt * kf[j];
    k0 = n0; k1 = n1; p = pn;
  }
  float L = l;
  L += __shfl_xor(L, 16); L += __shfl_xor(L, 32);
  #pragma unroll
  for (int j = 0; j < 16; ++j){
    float x = a[j];
    x += __shfl_xor(x, 16); x += __shfl_xor(x, 32);
    a[j] = x;
  }
  float linv = 0.f, coef = 0.f;
  if (deg > 0){ linv = 1.0f / L; coef = -lam2 * 0.0625f * linv; }
  if (lane == 0){
    float2 ml; ml.x = 0.f; ml.y = linv;
    ml2[r] = ml;
  }
  if (quarter == 0){
    ushort_t* dst = dstage + ((unsigned)r << 9) + subo;
    uint4 p0, p1;
    p0.x = pack2(coef*a[0], coef*a[1]);   p0.y = pack2(coef*a[2], coef*a[3]);
    p0.z = pack2(coef*a[4], coef*a[5]);   p0.w = pack2(coef*a[6], coef*a[7]);
    p1.x = pack2(coef*a[8], coef*a[9]);   p1.y = pack2(coef*a[10], coef*a[11]);
    p1.z = pack2(coef*a[12], coef*a[13]); p1.w = pack2(coef*a[14], coef*a[15]);
    *(uint4*)dst = p0; *(uint4*)(dst + 8) = p1;
  }
}

// ---------- order-2 by-u: pe = stored exp(s) * linv, 32-bit offsets, prefetch ----------
__global__ __launch_bounds__(256) void e2_rowu(const ushort_t* __restrict__ QK2, const int* __restrict__ cntU,
    const int* __restrict__ adju, const float* __restrict__ s2e, const float2* __restrict__ ml2,
    ushort_t* __restrict__ dstage, const float* __restrict__ l2p)
{
  int wave = threadIdx.x >> 6, lane = threadIdx.x & 63;
  int r = blockIdx.x * 4 + wave;
  int quarter = lane >> 4, sub = lane & 15;
  float lam2 = softplus_f(*l2p);
  int start = r << 7;
  int deg = cntU[r]; if (deg > CAP2) deg = CAP2;
  int end = start + deg;
  unsigned subo = (unsigned)sub * 16u;
  float a[16] = {};
  int p = start + quarter;
  uint4 q0a, q0b; float sv0 = 0.f; float2 mlv0 = {0.f, 0.f};
  if (p < end){
    unsigned gs = (unsigned)adju[p];
    unsigned c = gs >> 7;
    sv0 = s2e[gs]; mlv0 = ml2[c];
    unsigned off = (c << 9) + subo;
    q0a = *(const uint4*)(QK2 + off); q0b = *(const uint4*)(QK2 + off + 8);
  }
  while (p < end){
    int pn = p + 4;
    uint4 q1a, q1b; float sv1 = 0.f; float2 mlv1 = {0.f, 0.f};
    if (pn < end){
      unsigned gs = (unsigned)adju[pn];
      unsigned c = gs >> 7;
      sv1 = s2e[gs]; mlv1 = ml2[c];
      unsigned off = (c << 9) + subo;
      q1a = *(const uint4*)(QK2 + off); q1b = *(const uint4*)(QK2 + off + 8);
    }
    float pe = sv0 * mlv0.y;
    float qf[16];
    unpack16(q0a, q0b, qf);
    #pragma unroll
    for (int j = 0; j < 16; ++j) a[j] += pe * qf[j];
    q0a = q1a; q0b = q1b; sv0 = sv1; mlv0 = mlv1; p = pn;
  }
  #pragma unroll
  for (int j = 0; j < 16; ++j){
    float x = a[j];
    x += __shfl_xor(x, 16); x += __shfl_xor(x, 32);
    a[j] = x;
  }
  float coef = -lam2 * 0.0625f;
  if (quarter == 0){
    ushort_t* dst = dstage + ((unsigned)r << 9) + 256u + subo;
    uint4 p0, p1;
    p0.x = pack2(coef*a[0], coef*a[1]);   p0.y = pack2(coef*a[2], coef*a[3]);
    p0.z = pack2(coef*a[4], coef*a[5]);   p0.w = pack2(coef*a[6], coef*a[7]);
    p1.x = pack2(coef*a[8], coef*a[9]);   p1.y = pack2(coef*a[10], coef*a[11]);
    p1.z = pack2(coef*a[12], coef*a[13]); p1.w = pack2(coef*a[14], coef*a[15]);
    *(uint4*)dst = p0; *(uint4*)(dst + 8) = p1;
  }
}

// ---------- order-3 by-c: no-max softmax, 32-bit offsets, prefetch, wave per row, T in LDS ----------
// s3c stores exp(s); ml3 = {0, 1/L}.
__global__ __launch_bounds__(256) void e3_rowc(const ushort_t* __restrict__ QK3, const float* __restrict__ Tt,
    const int* __restrict__ cnt3C, const unsigned* __restrict__ adj3c, ushort_t* __restrict__ dstage,
    float* __restrict__ s3c, float2* __restrict__ ml3, const float* __restrict__ b3p,
    const float* __restrict__ l3p)
{
  __shared__ float sT[1024];
  int wave = threadIdx.x >> 6, lane = threadIdx.x & 63;
  int r = blockIdx.x * 4 + wave;
  for (int i = threadIdx.x; i < 1024; i += 256) sT[i] = Tt[i];
  __syncthreads();
  float b3s = fminf(softplus_f(*b3p), 5.0f) * 0.0625f;
  float lam3 = softplus_f(*l3p);
  int start = r << 4;
  int deg = cnt3C[r]; if (deg > CAP3C) deg = CAP3C;
  int end = start + deg;
  unsigned laneo = (unsigned)lane * 8u;
  uint4 qw = *(const uint4*)(QK3 + ((unsigned)r << 10) + laneo);
  float q[8] = {bflo(qw.x),bfhi(qw.x),bflo(qw.y),bfhi(qw.y),bflo(qw.z),bfhi(qw.z),bflo(qw.w),bfhi(qw.w)};
  #pragma unroll
  for (int j = 0; j < 8; ++j) q[j] *= b3s;   // fold scale
  float T0[8], T1[8];
  #pragma unroll
  for (int j = 0; j < 8; ++j){ T0[j] = sT[lane * 8 + j]; T1[j] = sT[512 + lane * 8 + j]; }
  float l = 0.f;
  float a[8] = {};
  int p = start;
  unsigned ent0 = 0; uint4 bw0, cw0;
  if (p < end){
    ent0 = adj3c[p];
    unsigned u = ent0 & 32767u, v = (ent0 >> 15) & 32767u;
    bw0 = *(const uint4*)(QK3 + (u << 10) + 512u + laneo);
    cw0 = *(const uint4*)(QK3 + (v << 10) + 512u + laneo);
  }
  while (p < end){
    int pn = p + 1;
    unsigned ent1 = 0; uint4 bw1, cw1;
    if (pn < end){
      ent1 = adj3c[pn];
      unsigned u = ent1 & 32767u, v = (ent1 >> 15) & 32767u;
      bw1 = *(const uint4*)(QK3 + (u << 10) + 512u + laneo);
      cw1 = *(const uint4*)(QK3 + (v << 10) + 512u + laneo);
    }
    int tau = (ent0 >> 30) & 1;
    float kb[8] = {bflo(bw0.x),bfhi(bw0.x),bflo(bw0.y),bfhi(bw0.y),bflo(bw0.z),bfhi(bw0.z),bflo(bw0.w),bfhi(bw0.w)};
    float kc[8] = {bflo(cw0.x),bfhi(cw0.x),bflo(cw0.y),bfhi(cw0.y),bflo(cw0.z),bfhi(cw0.z),bflo(cw0.w),bfhi(cw0.w)};
    float prod[8];
    float d = 0.f;
    #pragma unroll
    for (int j = 0; j < 8; ++j){
      float tj = tau ? T1[j] : T0[j];
      prod[j] = kb[j] * kc[j] * tj;
      d += q[j] * prod[j];
    }
    #pragma unroll
    for (int o = 32; o > 0; o >>= 1) d += __shfl_xor(d, o);
    float pt = __expf(d);
    if (lane == 0) s3c[p] = pt;
    l += pt;
    #pragma unroll
    for (int j = 0; j < 8; ++j) a[j] += pt * prod[j];
    ent0 = ent1; bw0 = bw1; cw0 = cw1; p = pn;
  }
  float linv = 0.f, coef = 0.f;
  if (deg > 0){ linv = 1.0f / l; coef = -lam3 * 0.0625f * linv; }
  uint4 o4;
  o4.x = pack2(coef*a[0], coef*a[1]); o4.y = pack2(coef*a[2], coef*a[3]);
  o4.z = pack2(coef*a[4], coef*a[5]); o4.w = pack2(coef*a[6], coef*a[7]);
  *(uint4*)(dstage + ((unsigned)r << 10) + laneo) = o4;
  if (lane == 0){
    float2 ml; ml.x = 0.f; ml.y = linv;
    ml3[r] = ml;
  }
}

// ---------- order-3 incidence: pe = stored exp(s) * linv, 32-bit offsets, prefetch, T in LDS ----------
__global__ __launch_bounds__(256) void e3_rowi(const ushort_t* __restrict__ QK3, const float* __restrict__ Tt,
    const int* __restrict__ cnt3I, const uint2* __restrict__ adj3i, const float* __restrict__ s3c,
    const float2* __restrict__ ml3, ushort_t* __restrict__ dstage, const float* __restrict__ l3p)
{
  __shared__ float sT[1024];
  int wave = threadIdx.x >> 6, lane = threadIdx.x & 63;
  int r = blockIdx.x * 4 + wave;
  for (int i = threadIdx.x; i < 1024; i += 256) sT[i] = Tt[i];
  __syncthreads();
  float lam3 = softplus_f(*l3p);
  int start = r << 5;
  int deg = cnt3I[r]; if (deg > CAP3I) deg = CAP3I;
  int end = start + deg;
  unsigned laneo = (unsigned)lane * 8u;
  float T0[8], T1[8];
  #pragma unroll
  for (int j = 0; j < 8; ++j){ T0[j] = sT[lane * 8 + j]; T1[j] = sT[512 + lane * 8 + j]; }
  float a[8] = {};
  int p = start;
  uint2 e0; uint4 qw0, ow0; float sv0 = 0.f; float2 mlv0 = {0.f, 0.f};
  if (p < end){
    e0 = adj3i[p];
    unsigned c = e0.x & 32767u, other = (e0.x >> 16) & 32767u;
    sv0 = s3c[e0.y]; mlv0 = ml3[c];
    qw0 = *(const uint4*)(QK3 + (c << 10) + laneo);
    ow0 = *(const uint4*)(QK3 + (other << 10) + 512u + laneo);
  }
  while (p < end){
    int pn = p + 1;
    uint2 e1; uint4 qw1, ow1; float sv1 = 0.f; float2 mlv1 = {0.f, 0.f};
    if (pn < end){
      e1 = adj3i[pn];
      unsigned c = e1.x & 32767u, other = (e1.x >> 16) & 32767u;
      sv1 = s3c[e1.y]; mlv1 = ml3[c];
      qw1 = *(const uint4*)(QK3 + (c << 10) + laneo);
      ow1 = *(const uint4*)(QK3 + (other << 10) + 512u + laneo);
    }
    int tau = (e0.x >> 15) & 1;
    float pe = sv0 * mlv0.y;
    float q[8] = {bflo(qw0.x),bfhi(qw0.x),bflo(qw0.y),bfhi(qw0.y),bflo(qw0.z),bfhi(qw0.z),bflo(qw0.w),bfhi(qw0.w)};
    float ko[8] = {bflo(ow0.x),bfhi(ow0.x),bflo(ow0.y),bfhi(ow0.y),bflo(ow0.z),bfhi(ow0.z),bflo(ow0.w),bfhi(ow0.w)};
    #pragma unroll
    for (int j = 0; j < 8; ++j){
      float tj = tau ? T1[j] : T0[j];
      a[j] += pe * q[j] * ko[j] * tj;
    }
    e0 = e1; qw0 = qw1; ow0 = ow1; sv0 = sv1; mlv0 = mlv1; p = pn;
  }
  float coef = -lam3 * 0.0625f;
  uint4 o4;
  o4.x = pack2(coef*a[0], coef*a[1]); o4.y = pack2(coef*a[2], coef*a[3]);
  o4.z = pack2(coef*a[4], coef*a[5]); o4.w = pack2(coef*a[6], coef*a[7]);
  *(uint4*)(dstage + ((unsigned)r << 10) + 512u + laneo) = o4;
}

// ---------- LN backward + clips + update ----------
__global__ __launch_bounds__(256) void ln_bwd_update(const float* __restrict__ X, const float* __restrict__ dG,
    const float* __restrict__ gamma, const float* __restrict__ mean, const float* __restrict__ rstd,
    const float* __restrict__ step_p, float* __restrict__ out)
{
  __shared__ float sbuf[8];
  int n = blockIdx.x, t = threadIdx.x;
  size_t idx = (size_t)n * D_ + t;
  float x = X[idx];
  float rs = rstd[n];
  float xh = (x - mean[n]) * rs;
  float dxh = dG[idx] * gamma[t];
  float s1 = block_reduce_sum(dxh, sbuf) * (1.0f / D_);
  float s2v = block_reduce_sum(dxh * xh, sbuf) * (1.0f / D_);
  float dx = rs * (dxh - s1 - xh * s2v);
  float gn2 = block_reduce_sum(dx * dx, sbuf);
  float gn = fmaxf(sqrtf(gn2), 1e-6f);
  float gsc = fminf(1.0f / gn, 1.0f);
  float stp = step_p[0] * 0.9999f;
  float xn = x - stp * gsc * dx;
  float sn2 = block_reduce_sum(xn * xn, sbuf);
  float sn = fmaxf(sqrtf(sn2), 1e-6f);
  float ssc = fminf(10.0f / sn, 1.0f);
  out[idx] = xn * ssc;
}

// ---------- parallel energy partial reduction: atomicAdd into eacc[0..2] ----------
__global__ __launch_bounds__(256) void energy_partial(const float2* __restrict__ ml2, const float2* __restrict__ ml3,
    const float* __restrict__ lseM, int n, float* __restrict__ eacc)
{
  __shared__ float sbuf[8];
  int t = threadIdx.x;
  float a2 = 0.f, a3 = 0.f, am = 0.f;
  for (int i = blockIdx.x * 256 + t; i < n; i += gridDim.x * 256){
    float2 v2 = ml2[i];
    if (v2.y > 0.f) a2 += v2.x - logf(v2.y);
    float2 v3 = ml3[i];
    if (v3.y > 0.f) a3 += v3.x - logf(v3.y);
    am += lseM[i];
  }
  float s2 = block_reduce_sum(a2, sbuf);
  float s3 = block_reduce_sum(a3, sbuf);
  float sm = block_reduce_sum(am, sbuf);
  if (t == 0){
    atomicAdd(eacc + 0, s2);
    atomicAdd(eacc + 1, s3);
    atomicAdd(eacc + 2, sm);
  }
}

// ---------- final combine ----------
__global__ __launch_bounds__(64) void energy_combine(const float* __restrict__ eacc,
    const float* l2p, const float* l3p, const float* lmp,
    const float* b2p, const float* b3p, const float* bmp, float* __restrict__ outE)
{
  if (threadIdx.x == 0){
    float l2 = softplus_f(*l2p), l3 = softplus_f(*l3p), lm = softplus_f(*lmp);
    float b2 = fminf(softplus_f(*b2p), 5.0f);
    float b3 = fminf(softplus_f(*b3p), 5.0f);
    float bm = fminf(softplus_f(*bmp), 5.0f);
    *outE = -(l2 / b2) * eacc[0] - (l3 / b3) * eacc[1] - (lm / bm) * eacc[2];
  }
}

static inline void zfill(void* p, size_t nElems, hipStream_t stream){
  size_t n4 = nElems / 4;
  int blocks = (int)(((n4 + 255) / 256) < 16384 ? ((n4 + 255) / 256) : 16384);
  if (blocks < 1) blocks = 1;
  zerok<<<blocks, 256, 0, stream>>>((float4*)p, n4);
}

extern "C" void kernel_launch(void* const* d_in, const int* in_sizes, int n_in,
                              void* d_out, int out_size, void* d_ws, size_t ws_size,
                              hipStream_t stream)
{
  const float* X     = (const float*)d_in[0];
  const int*   c2    = (const int*)d_in[1];
  const int*   u2    = (const int*)d_in[2];
  const int*   c3    = (const int*)d_in[3];
  const int*   u3    = (const int*)d_in[4];
  const int*   v3    = (const int*)d_in[5];
  const int*   tt    = (const int*)d_in[6];
  const float* stepp = (const float*)d_in[7];
  const float* gamma = (const float*)d_in[8];
  const float* beta  = (const float*)d_in[9];
  const float* W_Q2  = (const float*)d_in[10];
  const float* W_K2  = (const float*)d_in[11];
  const float* W_Q3  = (const float*)d_in[12];
  const float* W_K3  = (const float*)d_in[13];
  const float* T_tau = (const float*)d_in[14];
  const float* W_Qm  = (const float*)d_in[15];
  const float* W_Km  = (const float*)d_in[16];
  const float* B_mem = (const float*)d_in[17];
  const float* l2p   = (const float*)d_in[18];
  const float* l3p   = (const float*)d_in[19];
  const float* lmp   = (const float*)d_in[20];
  const float* b2p   = (const float*)d_in[21];
  const float* b3p   = (const float*)d_in[22];
  const float* bmp   = (const float*)d_in[23];

  const int N  = in_sizes[0] / D_;
  const int NE = in_sizes[1];
  const int NT = in_sizes[3];
  const size_t ND = (size_t)N * D_;

  // ---- byte arena ----
  char* base = (char*)d_ws;
  size_t off = 0;
  auto alloc = [&](size_t bytes) -> void* {
    void* p = base + off;
    off += (bytes + 255) & ~(size_t)255;
    return p;
  };
  ushort_t* Gb    = (ushort_t*)alloc(ND * 2);                    // 16 MB
  ushort_t* bufA  = (ushort_t*)alloc(ND * 4 * 2);                // 64 MB
  ushort_t* bufB  = (ushort_t*)alloc(ND * 4 * 2);                // 64 MB (o2: dstage 32MB | s2e 16MB)
  int*      zreg  = (int*)     alloc(((size_t)4 * N + 16) * 4);  // cntC|cntU|cnt3C|cnt3I|eacc
  ushort_t* adjc  = (ushort_t*)alloc((size_t)N * CAP2 * 2);      // 8 MB (ushort entries)
  int*      adju  = (int*)     alloc((size_t)N * CAP2 * 4);      // 16 MB
  unsigned* adj3c = (unsigned*)alloc((size_t)N * CAP3C * 4);     // 2 MB
  uint2*    adj3i = (uint2*)   alloc((size_t)N * CAP3I * 8);     // 8 MB
  float*    s3c   = (float*)   alloc((size_t)N * CAP3C * 4);     // 2 MB
  float2*   ml2   = (float2*)  alloc((size_t)N * 8);
  float2*   ml3   = (float2*)  alloc((size_t)N * 8);
  ushort_t* Kmb   = (ushort_t*)alloc((size_t)128 * 256 * 2);
  ushort_t* KWb   = (ushort_t*)alloc((size_t)256 * 128 * 2);
  float*    meanb = (float*)   alloc((size_t)N * 4);
  float*    rstdb = (float*)   alloc((size_t)N * 4);
  float*    lseM  = (float*)   alloc((size_t)N * 4);
  ushort_t* WtQm  = (ushort_t*)alloc(65536 * 2);
  ushort_t* WtF2  = (ushort_t*)alloc(131072 * 2);
  ushort_t* WtF3  = (ushort_t*)alloc(262144 * 2);
  ushort_t* WbQm  = (ushort_t*)alloc(65536 * 2);
  ushort_t* Bt2   = (ushort_t*)alloc(131072 * 2);
  ushort_t* Bt3   = (ushort_t*)alloc(262144 * 2);

  int* cntC  = zreg;
  int* cntU  = zreg + N;
  int* cnt3C = zreg + 2 * N;
  int* cnt3I = zreg + 3 * N;
  float* eacc = (float*)(zreg + 4 * N);
  float* out = (float*)d_out;
  float*    Sm  = (float*)bufB;                          // mem phase
  ushort_t* Pb  = (ushort_t*)(Sm + (size_t)N * 128);
  float*    s2e = (float*)(bufB + ND * 2);               // o2 phase: upper 32MB of bufB

  // order-2 build scratch aliased into bufA (dead before the first GEMM writes bufA)
  unsigned* partA  = (unsigned*)bufA;                                 // 8MB: part_c then part_u (uint2)
  uint2*    pairsU = (uint2*)((char*)bufA + ((size_t)8 << 20));       // 8MB
  unsigned* bhC    = (unsigned*)((char*)bufA + ((size_t)16 << 20));   // 256KB
  unsigned* bhU    = bhC + NBP * 256;                                 // 256KB
  unsigned* baseC  = bhU + NBP * 256;                                 // 257 words
  unsigned* baseU  = baseC + 512;

  zfill(zreg, (size_t)4 * N + 16, stream);

  // 1. LN forward + weight prep
  ln_fwd<<<N, 256, 0, stream>>>(X, gamma, beta, Gb, meanb, rstdb);
  wprep_all<<<(917504 + 255) / 256, 256, 0, stream>>>(W_Q2, W_K2, W_Q3, W_K3, W_Qm,
      WtQm, WtF2, WtF3, WbQm, Bt2, Bt3);

  // CSR build order-2: deterministic bucketed build, coalesced writes, zero global atomics
  {
    int chunk = (NE + NBP - 1) / NBP;
    p2_hist<<<NBP, 256, 0, stream>>>((const unsigned*)c2, 1, NE, chunk, bhC);
    p2_scan<<<1, 256, 0, stream>>>(bhC, NBP, baseC);
    p2_place_c<<<NBP, 256, 0, stream>>>(c2, u2, NE, chunk, bhC, partA);
    p2_fine_c<<<NBUCK, 256, 0, stream>>>(partA, baseC, adjc, cntC, pairsU);
    p2_hist<<<NBP, 256, 0, stream>>>((const unsigned*)pairsU, 2, NE, chunk, bhU);
    p2_scan<<<1, 256, 0, stream>>>(bhU, NBP, baseU);
    p2_place_u<<<NBP, 256, 0, stream>>>(pairsU, NE, chunk, bhU, (uint2*)partA);
    p2_fine_u<<<NBUCK, 256, 0, stream>>>((const uint2*)partA, baseU, adju, cntU);
  }
  // order-3 build (small)
  scatter3<<<(NT + 255) / 256, 256, 0, stream>>>(c3, u3, v3, tt, cnt3C, cnt3I, adj3c, adj3i, NT);

  dim3 g256(2, N / 128), g512(4, N / 128), g1024(8, N / 128);

  // 2. memory phase (GEMM-shaped)
  km_kernel<<<128, 256, 0, stream>>>(B_mem, W_Km, Kmb);
  gemm_bt_mfma<2><<<dim3(1, 2), 256, 0, stream>>>(WbQm, Kmb, KWb, 256, 128);
  gemm_bt_mfma<2><<<g256, 256, 0, stream>>>(Gb, WtQm, bufA, D_, D_);
  gemm_bt_mfma<0><<<dim3(1, N / 128), 256, 0, stream>>>(bufA, Kmb, Sm, 256, 128);
  softmax32<<<N / 8, 256, 0, stream>>>(Sm, Pb, lseM, bmp, lmp);
  gemm_bt_mfma<0><<<g256, 256, 0, stream>>>(Pb, KWb, out, 128, D_);

  // 3. order-2 phase
  gemm_bt_mfma<2><<<g512, 256, 0, stream>>>(Gb, WtF2, bufA, D_, 512);
  e2_rowc<<<N / 4, 256, 0, stream>>>(bufA, cntC, adjc, bufB, s2e, ml2, b2p, l2p);
  e2_rowu<<<N / 4, 256, 0, stream>>>(bufA, cntU, adju, s2e, ml2, bufB, l2p);
  gemm_bt_mfma<1><<<g256, 256, 0, stream>>>(bufB, Bt2, out, 512, D_);

  // 4. order-3 phase
  gemm_bt_mfma<2><<<g1024, 256, 0, stream>>>(Gb, WtF3, bufA, D_, 1024);
  e3_rowc<<<N / 4, 256, 0, stream>>>(bufA, T_tau, cnt3C, adj3c, bufB, s3c, ml3, b3p, l3p);
  e3_rowi<<<N / 4, 256, 0, stream>>>(bufA, T_tau, cnt3I, adj3i, s3c, ml3, bufB, l3p);
  gemm_bt_mfma<1><<<g256, 256, 0, stream>>>(bufB, Bt3, out, 1024, D_);

  // 5. LN backward + clips + update
  ln_bwd_update<<<N, 256, 0, stream>>>(X, out, gamma, meanb, rstdb, stepp, out);

  // 6. energy: parallel partial + tiny combine
  energy_partial<<<128, 256, 0, stream>>>(ml2, ml3, lseM, N, eacc);
  energy_combine<<<1, 64, 0, stream>>>(eacc, l2p, l3p, lmp, b2p, b3p, bmp, out + ND);
}